// Round 1
// 204.202 us; speedup vs baseline: 1.0342x; 1.0342x over previous
//
#include <hip/hip_runtime.h>
#include <hip/hip_bf16.h>
#include <hip/hip_fp16.h>

#define EPS 1e-8f
#define PI_F 3.14159265358979323846f

typedef _Float16 half8 __attribute__((ext_vector_type(8)));
typedef _Float16 half4 __attribute__((ext_vector_type(4)));
typedef float f32x4 __attribute__((ext_vector_type(4)));
typedef float f32x2 __attribute__((ext_vector_type(2)));

__device__ __forceinline__ float gelu_exact(float v) {
    return 0.5f * v * (1.0f + erff(v * 0.70710678118654752f));
}

// ---------------------------------------------------------------------------
// Kernel 0: embed_w [256 k,512 col] fp32 -> fragment-ordered fp16 hi/lo tiles
// Wth/Wtl laid out [g(4)][kt(8)][r(128)][k(32)] so gemm_embed's waves can
// global_load_dwordx4 B fragments straight from L2 (no LDS round-trip).
// Row order within a g-tile: r = (dl>>5)*64 + is_h2*32 + (dl&31)  so each
// wn-half (64 rows) holds h1 rows [0,32) and h2 rows [32,64) for 32 d's --
// every wave sees both halves of its d's (epilogue stays wave-local).
// Also zero-inits XMsum/YMsum/pooled.
// ---------------------------------------------------------------------------
__global__ void convertW(const float* __restrict__ W,
                         _Float16* __restrict__ Wth, _Float16* __restrict__ Wtl,
                         float* __restrict__ zero_base) {
    int idx = blockIdx.x * 256 + threadIdx.x;   // 0..131071
    if (idx < 49152) zero_base[idx] = 0.f;      // XMsum,YMsum,pooled
    int col = idx & 511, k = idx >> 9;
    int d  = col & 255;
    int g  = d >> 6;
    int dl = d & 63;
    int r  = (dl >> 5) * 64 + ((col >> 8) << 5) + (dl & 31);
    int kt = k >> 5, ko = k & 31;
    float f = W[k * 512 + col];
    _Float16 h = (_Float16)f;
    int o = ((g * 8 + kt) * 128 + r) * 32 + ko;
    Wth[o] = h;
    Wtl[o] = (_Float16)(f - (float)h);
}

// ---------------------------------------------------------------------------
// Kernel 1: embed GEMM, 3-pass fp16 split (Ah*Bh + Ah*Bl + Al*Bh), fused
// polar transform. Tile 128m x 128n. NEW: 2x2 wave layout (each wave owns
// 64m x 64n) and B fragments loaded directly from global/L2 in fragment
// order. LDS only stages A (16 KB). LDS b128 ops per wave per K-step drop
// 28 -> 12 (the old kernel was LDS-pipe-bound: 28 insts * ~12cyc * 16 waves
// >> 920 cyc of MFMA per SIMD).
// XCD swizzle unchanged: 4 g-blocks of one m-tile co-resident on one XCD.
// ---------------------------------------------------------------------------
__global__ __launch_bounds__(256, 4) void gemm_embed(
    const float* __restrict__ x,
    const _Float16* __restrict__ Wth, const _Float16* __restrict__ Wtl,
    const float* __restrict__ bias,
    unsigned short* __restrict__ XY8,
    float* __restrict__ XMsum, float* __restrict__ YMsum)
{
    __shared__ __attribute__((aligned(16))) _Float16 Ah[4096], Al[4096];
    const int tid  = threadIdx.x;
    const int wave = tid >> 6;
    const int lane = tid & 63;
    const int wm   = wave >> 1;              // m-half of the 128 rows
    const int wn   = wave & 1;               // n-half of the 128 B-rows
    const int id   = blockIdx.x;
    const int xcd  = id & 7;
    const int s    = id >> 3;
    const int g    = s & 3;                  // d-range [64g, 64g+64)
    const int mt   = (s >> 2) * 8 + xcd;     // 0..511
    const int m0   = mt * 128;
    const int q    = lane >> 4, ln = lane & 15;

    f32x4 acc[4][4];
#pragma unroll
    for (int mi = 0; mi < 4; ++mi)
#pragma unroll
        for (int nt = 0; nt < 4; ++nt)
            acc[mi][nt] = (f32x4){0.f, 0.f, 0.f, 0.f};

    for (int kt = 0; kt < 8; ++kt) {
        // ---- B fragments straight from global (L2-resident, 0.5 MB) ----
        half8 bh[4], bl[4];
        {
            const int tbase = (g * 8 + kt) * 4096;
#pragma unroll
            for (int nt = 0; nt < 4; ++nt) {
                int off = tbase + (wn * 64 + nt * 16 + ln) * 32 + q * 8;
                bh[nt] = *(const half8*)(Wth + off);
                bl[nt] = *(const half8*)(Wtl + off);
            }
        }
        __syncthreads();
        // ---- stage A tile [128 m][32 k]: fp32 -> fp16 hi + lo residual ----
#pragma unroll
        for (int L = 0; L < 2; ++L) {
            int idx2 = L * 256 + tid;
            int r = idx2 >> 2, cq = idx2 & 3;
            const float* src = x + (size_t)(m0 + r) * 256 + kt * 32 + cq * 8;
            const float4 f0 = *(const float4*)(src);
            const float4 f1 = *(const float4*)(src + 4);
            half8 hh, ll;
            hh[0] = (_Float16)f0.x; ll[0] = (_Float16)(f0.x - (float)hh[0]);
            hh[1] = (_Float16)f0.y; ll[1] = (_Float16)(f0.y - (float)hh[1]);
            hh[2] = (_Float16)f0.z; ll[2] = (_Float16)(f0.z - (float)hh[2]);
            hh[3] = (_Float16)f0.w; ll[3] = (_Float16)(f0.w - (float)hh[3]);
            hh[4] = (_Float16)f1.x; ll[4] = (_Float16)(f1.x - (float)hh[4]);
            hh[5] = (_Float16)f1.y; ll[5] = (_Float16)(f1.y - (float)hh[5]);
            hh[6] = (_Float16)f1.z; ll[6] = (_Float16)(f1.z - (float)hh[6]);
            hh[7] = (_Float16)f1.w; ll[7] = (_Float16)(f1.w - (float)hh[7]);
            int pos = cq ^ ((r >> 1) & 3);
            *(half8*)&Ah[r * 32 + pos * 8] = hh;
            *(half8*)&Al[r * 32 + pos * 8] = ll;
        }
        __syncthreads();

        // ---- A fragments (rows wm*64 .. wm*64+63) ----
        half8 am[4];
#pragma unroll
        for (int mi = 0; mi < 4; ++mi) {
            int row = wm * 64 + mi * 16 + ln;
            am[mi] = *(const half8*)&Ah[row * 32 + (q ^ ((row >> 1) & 3)) * 8];
        }
        // pass 1: Ah*Bh
#pragma unroll
        for (int mi = 0; mi < 4; ++mi)
#pragma unroll
            for (int nt = 0; nt < 4; ++nt)
                acc[mi][nt] = __builtin_amdgcn_mfma_f32_16x16x32_f16(am[mi], bh[nt], acc[mi][nt], 0, 0, 0);
        // pass 2: Ah*Bl
#pragma unroll
        for (int mi = 0; mi < 4; ++mi)
#pragma unroll
            for (int nt = 0; nt < 4; ++nt)
                acc[mi][nt] = __builtin_amdgcn_mfma_f32_16x16x32_f16(am[mi], bl[nt], acc[mi][nt], 0, 0, 0);
        // pass 3: Al*Bh
#pragma unroll
        for (int mi = 0; mi < 4; ++mi) {
            int row = wm * 64 + mi * 16 + ln;
            half8 alv = *(const half8*)&Al[row * 32 + (q ^ ((row >> 1) & 3)) * 8];
#pragma unroll
            for (int nt = 0; nt < 4; ++nt)
                acc[mi][nt] = __builtin_amdgcn_mfma_f32_16x16x32_f16(alv, bh[nt], acc[mi][nt], 0, 0, 0);
        }
    }

    // ---- epilogue ----
    // B row order: nt=0 -> h1 of d0, nt=1 -> h1 of d1, nt=2 -> h2 of d0,
    // nt=3 -> h2 of d1 where d0 = g*64 + wn*32 + ln, d1 = d0 + 16.
    // C/D layout: col = lane&15, row = (lane>>4)*4 + reg  [m89 verified]
    const int d0 = g * 64 + wn * 32 + ln;
    const int d1 = d0 + 16;
    const int b  = m0 >> 10;
    const float b1_0 = bias[d0],       b1_1 = bias[d1];
    const float b2_0 = bias[256 + d0], b2_1 = bias[256 + d1];
    float sx0 = 0.f, sy0 = 0.f, sx1 = 0.f, sy1 = 0.f;
#pragma unroll
    for (int mi = 0; mi < 4; ++mi) {
#pragma unroll
        for (int i = 0; i < 4; ++i) {
            const int row = m0 + wm * 64 + mi * 16 + q * 4 + i;
            {
                const float h1 = acc[mi][0][i] + b1_0;
                const float h2 = acc[mi][2][i] + b2_0;
                const float rr = fabsf(h1) + 0.1f;
                float sv, cv;
                __sincosf(PI_F * h2, &sv, &cv);
                const float xc = rr * cv, yc = rr * sv;
                int pk = __builtin_amdgcn_cvt_pk_fp8_f32(xc, yc, 0, false);
                XY8[(size_t)row * 256 + d0] = (unsigned short)pk;
                sx0 += xc; sy0 += yc;
            }
            {
                const float h1 = acc[mi][1][i] + b1_1;
                const float h2 = acc[mi][3][i] + b2_1;
                const float rr = fabsf(h1) + 0.1f;
                float sv, cv;
                __sincosf(PI_F * h2, &sv, &cv);
                const float xc = rr * cv, yc = rr * sv;
                int pk = __builtin_amdgcn_cvt_pk_fp8_f32(xc, yc, 0, false);
                XY8[(size_t)row * 256 + d1] = (unsigned short)pk;
                sx1 += xc; sy1 += yc;
            }
        }
    }
    sx0 += __shfl_down(sx0, 32); sx0 += __shfl_down(sx0, 16);
    sy0 += __shfl_down(sy0, 32); sy0 += __shfl_down(sy0, 16);
    sx1 += __shfl_down(sx1, 32); sx1 += __shfl_down(sx1, 16);
    sy1 += __shfl_down(sy1, 32); sy1 += __shfl_down(sy1, 16);
    if (lane < 16) {
        atomicAdd(&XMsum[b * 256 + d0], sx0);
        atomicAdd(&YMsum[b * 256 + d0], sy0);
        atomicAdd(&XMsum[b * 256 + d1], sx1);
        atomicAdd(&YMsum[b * 256 + d1], sy1);
    }
}

// ---------------------------------------------------------------------------
// Kernel 2: 8-layer recurrence on the means. 8 threads per (b,d), 4 k-units
// each, shfl_xor(1,2,4) reduction.
// ---------------------------------------------------------------------------
__global__ __launch_bounds__(256) void layers_kernel(
    const float* __restrict__ XMsum, const float* __restrict__ YMsum,
    const float* __restrict__ mw1, const float* __restrict__ mb1,
    const float* __restrict__ mw2, const float* __restrict__ mb2,
    const float* __restrict__ pw1, const float* __restrict__ pb1,
    const float* __restrict__ pw2, const float* __restrict__ pb2,
    float* __restrict__ DX, float* __restrict__ DY)
{
    __shared__ float s_mw1[256], s_mb1[256], s_mw2[256], s_mb2[8];
    __shared__ float s_pw1[512], s_pb1[256], s_pw2[512], s_pb2[16];
    const int tid = threadIdx.x;
    s_mw1[tid] = mw1[tid]; s_mb1[tid] = mb1[tid];
    s_mw2[tid] = mw2[tid]; s_pb1[tid] = pb1[tid];
    s_pw1[tid] = pw1[tid]; s_pw1[256 + tid] = pw1[256 + tid];
    s_pw2[tid] = pw2[tid]; s_pw2[256 + tid] = pw2[256 + tid];
    if (tid < 8)  s_mb2[tid] = mb2[tid];
    if (tid < 16) s_pb2[tid] = pb2[tid];
    __syncthreads();

    const int gid = blockIdx.x * 256 + tid;
    const int idx = gid >> 3;                 // (b,d), 16384
    const int sub = gid & 7;                  // k-eighth
    float xm = XMsum[idx] * (1.0f / 1024.0f);
    float ym = YMsum[idx] * (1.0f / 1024.0f);
    float dxa = 0.f, dya = 0.f;
#pragma unroll 1
    for (int i = 0; i < 8; ++i) {
        float r2    = xm * xm + ym * ym;
        float r_agg = sqrtf(r2 + EPS);
        float hyp   = sqrtf(r2);
        float inv   = hyp > 0.f ? 1.0f / hyp : 0.f;
        float st    = ym * inv;
        float ct    = hyp > 0.f ? xm * inv : 1.0f;
        float log_r = logf(r_agg + EPS);
        float lr = 0.f, p0 = 0.f, p1 = 0.f;
#pragma unroll
        for (int k4 = 0; k4 < 4; ++k4) {
            int k = sub * 4 + k4;
            float hm = gelu_exact(log_r * s_mw1[i * 32 + k] + s_mb1[i * 32 + k]);
            lr += hm * s_mw2[i * 32 + k];
            float hp = gelu_exact(st * s_pw1[i * 64 + k] + ct * s_pw1[i * 64 + 32 + k] + s_pb1[i * 32 + k]);
            p0 += hp * s_pw2[i * 64 + 2 * k + 0];
            p1 += hp * s_pw2[i * 64 + 2 * k + 1];
        }
        lr += __shfl_xor(lr, 1); lr += __shfl_xor(lr, 2); lr += __shfl_xor(lr, 4);
        p0 += __shfl_xor(p0, 1); p0 += __shfl_xor(p0, 2); p0 += __shfl_xor(p0, 4);
        p1 += __shfl_xor(p1, 1); p1 += __shfl_xor(p1, 2); p1 += __shfl_xor(p1, 4);
        lr += s_mb2[i];
        p0 += s_pb2[i * 2 + 0];
        p1 += s_pb2[i * 2 + 1];
        float r_trans = expf(lr);
        float hp2  = sqrtf(p0 * p0 + p1 * p1);
        float invp = hp2 > 0.f ? 1.0f / hp2 : 0.f;
        float ctt  = hp2 > 0.f ? p1 * invp : 1.0f;
        float stt  = p0 * invp;
        float dx = r_trans * ctt;
        float dy = r_trans * stt;
        dxa += dx; dya += dy; xm += dx; ym += dy;
    }
    if (sub == 0) { DX[idx] = dxa; DY[idx] = dya; }
}

// ---------------------------------------------------------------------------
// Kernel 3: pooled[b,d] += sum_s sqrt((xc+DX)^2 + (yc+DY)^2 + EPS)
// XY8 packed fp8 pairs; 16B loads = 8 d's per thread. LDS reduce over the
// 8 s-subgroups (pad 9 -> conflict-free), 1 atomic per d.
// ---------------------------------------------------------------------------
__global__ __launch_bounds__(256) void pool_kernel(
    const unsigned short* __restrict__ XY8,
    const float* __restrict__ DX, const float* __restrict__ DY,
    float* __restrict__ pooled)
{
    __shared__ float red[256][9];
    const int b = blockIdx.x, sc = blockIdx.y, tid = threadIdx.x;
    const int dg = tid & 31;           // d-group: d = dg*8 .. dg*8+7
    const int sh = tid >> 5;           // s-subchunk (16 rows each)
    const int d0 = dg * 8;
    float dxv[8], dyv[8], s[8];
#pragma unroll
    for (int j = 0; j < 8; ++j) {
        dxv[j] = DX[b * 256 + d0 + j];
        dyv[j] = DY[b * 256 + d0 + j];
        s[j] = 0.f;
    }
    const int r0 = sc * 128 + sh * 16;
    const size_t base = ((size_t)b * 1024 + r0) * 256 + d0;
#pragma unroll 4
    for (int i = 0; i < 16; ++i) {
        const int4 v = *(const int4*)(XY8 + base + (size_t)i * 256);
        const int wv[4] = {v.x, v.y, v.z, v.w};
#pragma unroll
        for (int w = 0; w < 4; ++w) {
            f32x2 pa = __builtin_amdgcn_cvt_pk_f32_fp8(wv[w], false);
            f32x2 pb = __builtin_amdgcn_cvt_pk_f32_fp8(wv[w], true);
            float xa = pa[0] + dxv[2 * w],     ya = pa[1] + dyv[2 * w];
            float xb = pb[0] + dxv[2 * w + 1], yb = pb[1] + dyv[2 * w + 1];
            s[2 * w]     += sqrtf(xa * xa + ya * ya + EPS);
            s[2 * w + 1] += sqrtf(xb * xb + yb * yb + EPS);
        }
    }
#pragma unroll
    for (int j = 0; j < 8; ++j) red[tid][j] = s[j];
    __syncthreads();
    if (tid < 32) {
#pragma unroll
        for (int j = 0; j < 8; ++j) {
            float t = 0.f;
#pragma unroll
            for (int c = 0; c < 8; ++c) t += red[c * 32 + tid][j];
            atomicAdd(&pooled[b * 256 + tid * 8 + j], t);
        }
    }
}

// ---------------------------------------------------------------------------
// Kernel 4: classifier  gelu(pooled/1024 @ w1 + b1) @ w2 + b2  -> [64,1000]
// n-dim sliced across blockIdx.y (4 slices of 250) so the launch covers 256
// blocks instead of 64 (was latency-bound at 25% of CUs).
// ---------------------------------------------------------------------------
__global__ __launch_bounds__(256) void cls_kernel(
    const float* __restrict__ pooled,
    const float* __restrict__ w1, const float* __restrict__ b1,
    const float* __restrict__ w2, const float* __restrict__ b2,
    float* __restrict__ out)
{
    __shared__ float pl[256];
    __shared__ float part[8][32];
    __shared__ float hd[32];
    const int b = blockIdx.x, yc = blockIdx.y, tid = threadIdx.x;
    pl[tid] = pooled[b * 256 + tid] * (1.0f / 1024.0f);
    __syncthreads();
    const int hu = tid & 31, kc = tid >> 5;
    float a = 0.f;
    for (int k = kc * 32; k < kc * 32 + 32; ++k) a += pl[k] * w1[k * 32 + hu];
    part[kc][hu] = a;
    __syncthreads();
    if (tid < 32) {
        float s = b1[tid];
#pragma unroll
        for (int c = 0; c < 8; ++c) s += part[c][tid];
        hd[tid] = gelu_exact(s);
    }
    __syncthreads();
    const int n0 = yc * 250;
    const int nend = (n0 + 250 < 1000) ? n0 + 250 : 1000;
    for (int n = n0 + tid; n < nend; n += 256) {
        float s = b2[n];
#pragma unroll
        for (int k = 0; k < 32; ++k) s += hd[k] * w2[k * 1000 + n];
        out[b * 1000 + n] = s;
    }
}

// ---------------------------------------------------------------------------
extern "C" void kernel_launch(void* const* d_in, const int* in_sizes, int n_in,
                              void* d_out, int out_size, void* d_ws, size_t ws_size,
                              hipStream_t stream)
{
    const float* x       = (const float*)d_in[0];
    const float* embed_w = (const float*)d_in[1];
    const float* embed_b = (const float*)d_in[2];
    const float* mag_w1  = (const float*)d_in[3];
    const float* mag_b1  = (const float*)d_in[4];
    const float* mag_w2  = (const float*)d_in[5];
    const float* mag_b2  = (const float*)d_in[6];
    const float* ph_w1   = (const float*)d_in[7];
    const float* ph_b1   = (const float*)d_in[8];
    const float* ph_w2   = (const float*)d_in[9];
    const float* ph_b2   = (const float*)d_in[10];
    const float* cls_w1  = (const float*)d_in[11];
    const float* cls_b1  = (const float*)d_in[12];
    const float* cls_w2  = (const float*)d_in[13];
    const float* cls_b2  = (const float*)d_in[14];
    float* out = (float*)d_out;

    char* ws = (char*)d_ws;
    unsigned short* XY8 = (unsigned short*)(ws + 0);   // 33554432 B (fp8 pairs)
    _Float16* Wth = (_Float16*)(ws + 33554432);        // 262144
    _Float16* Wtl = (_Float16*)(ws + 33816576);        // 262144
    float* XMsum  = (float*)(ws + 34078720);           // 65536
    float* YMsum  = (float*)(ws + 34144256);           // 65536
    float* pooled = (float*)(ws + 34209792);           // 65536
    float* DX     = (float*)(ws + 34275328);           // 65536
    float* DY     = (float*)(ws + 34340864);           // 65536

    convertW<<<512, 256, 0, stream>>>(embed_w, Wth, Wtl, XMsum);  // zeros XMsum,YMsum,pooled (contiguous)
    gemm_embed<<<2048, 256, 0, stream>>>(x, Wth, Wtl, embed_b, XY8, XMsum, YMsum);
    layers_kernel<<<512, 256, 0, stream>>>(XMsum, YMsum, mag_w1, mag_b1, mag_w2, mag_b2,
                                           ph_w1, ph_b1, ph_w2, ph_b2, DX, DY);
    pool_kernel<<<dim3(64, 8), 256, 0, stream>>>(XY8, DX, DY, pooled);
    cls_kernel<<<dim3(64, 4), 256, 0, stream>>>(pooled, cls_w1, cls_b1, cls_w2, cls_b2, out);
}